// Round 2
// baseline (243.012 us; speedup 1.0000x reference)
//
#include <hip/hip_runtime.h>

#define F_DIM 128
#define TE_DIM 32
#define DD 160
#define NB 4096
#define KK 64
#define ROWS 2
#define LD 164        // padded fp32 row stride
#define TE_STRIDE 36  // padded half stride: 18 dwords, gcd(18,32)=2 -> <=2-way

// ws layout (float offsets)
#define WS_M   0          // [160][160]  (Wk^T Wq) / sqrt(160)
#define WS_V2  25600      // [160][160]  out_w @ Wv
#define WS_C   51200      // [160]       (Wk^T bq) / sqrt(160)
#define WS_U   51360      // [160]       (Wq^T bk) / sqrt(160)
#define WS_B2  51520      // [160]       out_w @ bv + out_b
#define WS_S0  51680      // [1]         (bq . bk) / sqrt(160)
#define WS_TOT 51681

__device__ __forceinline__ float dot4acc(const float4 w, const float4 v, float a) {
    a = fmaf(w.x, v.x, a);
    a = fmaf(w.y, v.y, a);
    a = fmaf(w.z, v.z, a);
    a = fmaf(w.w, v.w, a);
    return a;
}

__device__ __forceinline__ float wave_max(float v) {
    #pragma unroll
    for (int off = 32; off > 0; off >>= 1) v = fmaxf(v, __shfl_xor(v, off, 64));
    return v;
}
__device__ __forceinline__ float wave_sum(float v) {
    #pragma unroll
    for (int off = 32; off > 0; off >>= 1) v += __shfl_xor(v, off, 64);
    return v;
}

// ---------------- setup: fold weight matrices (runs every launch) ----------
__global__ void setup_kernel(const float* __restrict__ ipw, const float* __restrict__ ipb,
                             const float* __restrict__ ow,  const float* __restrict__ ob,
                             float* __restrict__ ws)
{
    const int g = blockIdx.x * blockDim.x + threadIdx.x;
    const float inv = 0.07905694150420949f;  // 1/sqrt(160)
    if (g < 25600) {
        const int e = g / DD, f = g % DD;
        const float* wk = ipw + DD * DD;
        float a = 0.f;
        for (int d = 0; d < DD; ++d) a = fmaf(wk[d * DD + e], ipw[d * DD + f], a);
        ws[WS_M + g] = a * inv;
    } else if (g < 51200) {
        const int gg = g - 25600;
        const int i = gg / DD, f = gg % DD;
        const float* wv = ipw + 2 * DD * DD;
        float a = 0.f;
        for (int d = 0; d < DD; ++d) a = fmaf(ow[i * DD + d], wv[d * DD + f], a);
        ws[WS_V2 + gg] = a;
    } else if (g < 51360) {
        const int e = g - 51200;
        const float* wk = ipw + DD * DD;
        float a = 0.f;
        for (int d = 0; d < DD; ++d) a = fmaf(wk[d * DD + e], ipb[d], a);
        ws[WS_C + e] = a * inv;
    } else if (g < 51520) {
        const int f = g - 51360;
        float a = 0.f;
        for (int d = 0; d < DD; ++d) a = fmaf(ipw[d * DD + f], ipb[DD + d], a);
        ws[WS_U + f] = a * inv;
    } else if (g < 51680) {
        const int i = g - 51520;
        float a = ob[i];
        for (int d = 0; d < DD; ++d) a = fmaf(ow[i * DD + d], ipb[2 * DD + d], a);
        ws[WS_B2 + i] = a;
    } else if (g == 51680) {
        float a = 0.f;
        for (int d = 0; d < DD; ++d) a = fmaf(ipb[d], ipb[DD + d], a);
        ws[WS_S0] = a * inv;
    }
}

// ---------------- main ------------------------------------------------------
__global__ __launch_bounds__(256, 8)
void structure_learner_kernel(
    const float* __restrict__ x,
    const int*   __restrict__ target_node_ids,
    const int*   __restrict__ target_node_times,
    const int*   __restrict__ neighbor_ids,
    const int*   __restrict__ edge_time,
    const float* __restrict__ edge_weight,
    const float* __restrict__ gumbel_u,
    const float* __restrict__ te_w,
    const float* __restrict__ te_b,
    const float* __restrict__ mlp_w,
    const float* __restrict__ mlp_b,
    const float* __restrict__ ws,
    float* __restrict__ out_ao,
    float* __restrict__ out_new,
    float* __restrict__ out_mask)
{
    __shared__ __attribute__((aligned(16))) float s_qin[ROWS][LD];
    __shared__ __attribute__((aligned(16))) float s_qt[ROWS][LD];
    __shared__ __attribute__((aligned(16))) float s_wkv[ROWS][2][LD];
    __shared__ __attribute__((aligned(16))) float s_ao[ROWS][LD];
    __shared__ float s_scores[ROWS][KK];
    __shared__ float s_attnw[ROWS][KK];
    __shared__ float s_et[ROWS][KK];
    __shared__ int   s_nid[ROWS][KK];
    __shared__ _Float16 s_te[ROWS][KK][TE_STRIDE];

    const int tid  = threadIdx.x;
    const int w    = tid >> 6;
    const int lane = tid & 63;
    const int r    = w >> 1;   // row within block (0..1)
    const int h    = w & 1;    // half (which of the 2 waves per row)
    const int b0   = blockIdx.x * ROWS;
    const int b    = b0 + r;

    const float* Mw = ws + WS_M;
    const float* V2 = ws + WS_V2;
    const float* Cv = ws + WS_C;
    const float* Uv = ws + WS_U;
    const float* B2 = ws + WS_B2;
    const float  s0 = ws[WS_S0];

    // ---- P0: load neighbor meta (h0) / build q_in (h1) ----
    if (h == 0) {
        s_nid[r][lane] = neighbor_ids[(long)b * KK + lane];
        s_et[r][lane]  = (float)edge_time[(long)b * KK + lane];
    } else {
        const int tn = target_node_ids[b];
        const float2 tx = *(const float2*)(x + (long)tn * F_DIM + lane * 2);
        s_qin[r][lane * 2]     = tx.x;
        s_qin[r][lane * 2 + 1] = tx.y;
        if (lane < TE_DIM) {
            const float tt = (float)target_node_times[b];
            s_qin[r][F_DIM + lane] = cosf(tt * te_w[lane] + te_b[lane]);
        }
    }
    __syncthreads();

    // ---- P1a: te table (each cos exactly once) ----
    {
        const int kl = h * 32 + (lane >> 1);
        const int fh = lane & 1;
        const float et = s_et[r][kl];
        #pragma unroll
        for (int j = 0; j < 16; ++j) {
            const int jj = fh * 16 + j;
            s_te[r][kl][jj] = (_Float16)cosf(et * te_w[jj] + te_b[jj]);
        }
    }
    // ---- P1b: q_tilde = M @ q_in + c  (256 threads, 2 rows) ----
    {
        const int r2 = tid & 1;
        const int dl = tid >> 1;  // 0..127
        const float4* v4 = (const float4*)s_qin[r2];
        const float4* w0 = (const float4*)(Mw + (long)dl * DD);
        float a0 = Cv[dl];
        if (dl < 32) {
            const float4* w1 = (const float4*)(Mw + (long)(dl + 128) * DD);
            float a1 = Cv[dl + 128];
            #pragma unroll 8
            for (int f = 0; f < 40; ++f) {
                const float4 v = v4[f];
                a0 = dot4acc(w0[f], v, a0);
                a1 = dot4acc(w1[f], v, a1);
            }
            s_qt[r2][dl]       = a0;
            s_qt[r2][dl + 128] = a1;
        } else {
            #pragma unroll 8
            for (int f = 0; f < 40; ++f) {
                const float4 v = v4[f];
                a0 = dot4acc(w0[f], v, a0);
            }
            s_qt[r2][dl] = a0;
        }
    }
    __syncthreads();

    // ---- P2: scores (2 waves/row: lane pair = one k, feature halves) ----
    {
        float p = s_qin[r][lane] * Uv[lane];
        p = fmaf(s_qin[r][lane + 64], Uv[lane + 64], p);
        if (lane < 32) p = fmaf(s_qin[r][128 + lane], Uv[128 + lane], p);
        const float sbk = wave_sum(p) + s0;

        const int kl = h * 32 + (lane >> 1);
        const int fh = lane & 1;
        const int nid = s_nid[r][kl];
        const float4* xr  = (const float4*)(x + (long)nid * F_DIM + fh * 64);
        const float4* qt4 = (const float4*)(s_qt[r] + fh * 64);
        float acc = 0.f;
        #pragma unroll
        for (int f = 0; f < 16; ++f) acc = dot4acc(xr[f], qt4[f], acc);
        const float* qte = s_qt[r] + F_DIM + fh * 16;
        const _Float16* te = &s_te[r][kl][fh * 16];
        #pragma unroll
        for (int j = 0; j < 16; ++j) acc = fmaf(qte[j], (float)te[j], acc);
        acc += __shfl_xor(acc, 1, 64);
        if (fh == 0) s_scores[r][kl] = acc + sbk;
    }
    __syncthreads();

    // ---- softmax (redundant per wave; lane = k) ----
    float aw;
    {
        const float sc = s_scores[r][lane];
        const float m = wave_max(sc);
        const float e = expf(sc - m);
        const float l = wave_sum(e);
        aw = e / l;
        if (h == 0) s_attnw[r][lane] = aw;
    }
    __syncthreads();

    // ---- P3: wkv partials (wave h covers k in [h*32, h*32+32)) ----
    {
        float ax = 0.f, ay = 0.f, at = 0.f;
        const float* xb = x + lane * 2;
        const int kbase = h * 32;
        #pragma unroll 4
        for (int kk = 0; kk < 32; ++kk) {
            const int k = kbase + kk;
            const float wgt = s_attnw[r][k];
            const int   nid = s_nid[r][k];
            const float2 xv = *(const float2*)(xb + (long)nid * F_DIM);
            ax = fmaf(wgt, xv.x, ax);
            ay = fmaf(wgt, xv.y, ay);
            if (lane < TE_DIM) at = fmaf(wgt, (float)s_te[r][k][lane], at);
        }
        s_wkv[r][h][lane * 2]     = ax;
        s_wkv[r][h][lane * 2 + 1] = ay;
        if (lane < TE_DIM) s_wkv[r][h][F_DIM + lane] = at;
    }
    __syncthreads();

    // ---- P4: ao = V2 @ (wkv0 + wkv1) + b2 ----
    {
        const int r2 = tid & 1;
        const int dl = tid >> 1;
        const float4* va = (const float4*)s_wkv[r2][0];
        const float4* vb = (const float4*)s_wkv[r2][1];
        const float4* w0 = (const float4*)(V2 + (long)dl * DD);
        float a0 = B2[dl];
        if (dl < 32) {
            const float4* w1 = (const float4*)(V2 + (long)(dl + 128) * DD);
            float a1 = B2[dl + 128];
            #pragma unroll 8
            for (int f = 0; f < 40; ++f) {
                const float4 p = va[f], q = vb[f];
                const float4 v = make_float4(p.x + q.x, p.y + q.y, p.z + q.z, p.w + q.w);
                a0 = dot4acc(w0[f], v, a0);
                a1 = dot4acc(w1[f], v, a1);
            }
            s_ao[r2][dl]       = a0;
            s_ao[r2][dl + 128] = a1;
        } else {
            #pragma unroll 8
            for (int f = 0; f < 40; ++f) {
                const float4 p = va[f], q = vb[f];
                const float4 v = make_float4(p.x + q.x, p.y + q.y, p.z + q.z, p.w + q.w);
                a0 = dot4acc(w0[f], v, a0);
            }
            s_ao[r2][dl] = a0;
        }
    }
    __syncthreads();

    // ---- epilogue ----
    if (h == 0) {
        float p = s_ao[r][lane] * mlp_w[lane];
        p = fmaf(s_ao[r][lane + 64], mlp_w[lane + 64], p);
        if (lane < 32) p = fmaf(s_ao[r][lane + 128], mlp_w[lane + 128], p);
        const float base = wave_sum(p) + mlp_b[0];

        const float u = gumbel_u[(long)b * KK + lane];
        const float g = -logf(-logf(u + 1e-10f) + 1e-10f);
        const float z = aw + g;  // TAU = 1.0
        const float m = wave_max(z);
        const float e = expf(z - m);
        const float l = wave_sum(e);
        out_mask[(long)b * KK + lane] = (e / l > 0.2f) ? 1.0f : 0.0f;

        const float ew  = edge_weight[(long)b * KK + lane];
        const float val = fmaf(ew, mlp_w[DD], base);
        out_new[(long)b * KK + lane] = (val >= 0.f) ? val : 0.01f * val;
    } else {
        float* ao = out_ao + (long)b * DD;
        ao[lane]      = s_ao[r][lane];
        ao[lane + 64] = s_ao[r][lane + 64];
        if (lane < 32) ao[lane + 128] = s_ao[r][lane + 128];
    }
}

extern "C" void kernel_launch(void* const* d_in, const int* in_sizes, int n_in,
                              void* d_out, int out_size, void* d_ws, size_t ws_size,
                              hipStream_t stream) {
    const float* x   = (const float*)d_in[0];
    const int*   tni = (const int*)d_in[1];
    const int*   tnt = (const int*)d_in[2];
    const int*   nid = (const int*)d_in[3];
    const int*   et  = (const int*)d_in[4];
    const float* ew  = (const float*)d_in[5];
    const float* gu  = (const float*)d_in[6];
    const float* tew = (const float*)d_in[7];
    const float* teb = (const float*)d_in[8];
    const float* ipw = (const float*)d_in[9];
    const float* ipb = (const float*)d_in[10];
    const float* ow  = (const float*)d_in[11];
    const float* ob  = (const float*)d_in[12];
    const float* mw  = (const float*)d_in[13];
    const float* mb  = (const float*)d_in[14];

    float* wsf = (float*)d_ws;

    float* out      = (float*)d_out;
    float* out_ao   = out;
    float* out_new  = out + (long)NB * DD;
    float* out_mask = out + (long)NB * DD + (long)NB * KK;

    setup_kernel<<<(WS_TOT + 255) / 256, 256, 0, stream>>>(ipw, ipb, ow, ob, wsf);

    structure_learner_kernel<<<NB / ROWS, 256, 0, stream>>>(
        x, tni, tnt, nid, et, ew, gu, tew, teb, mw, mb, wsf,
        out_ao, out_new, out_mask);
}

// Round 3
// 178.482 us; speedup vs baseline: 1.3615x; 1.3615x over previous
//
#include <hip/hip_runtime.h>

#define F_DIM 128
#define TE_DIM 32
#define DD 160
#define NB 4096
#define KK 64
#define ROWS 4
#define LD 164        // padded fp32 LDS row stride (164 % 32 = 4)
#define TE_STRIDE 36  // padded half stride: 18 dwords/row, 18*lane mod 32 -> 2-way max (free)

// ws layout (float offsets)
#define WS_M   0          // [160][160]  (Wk^T Wq) / sqrt(160)
#define WS_V2  25600      // [160][160]  out_w @ Wv
#define WS_C   51200      // [160]       (Wk^T bq) / sqrt(160)
#define WS_U   51360      // [160]       (Wq^T bk) / sqrt(160)
#define WS_B2  51520      // [160]       out_w @ bv + out_b
#define WS_S0  51680      // [1]         (bq . bk) / sqrt(160)
#define WS_TOT 51681

__device__ __forceinline__ float dot4acc(const float4 w, const float4 v, float a) {
    a = fmaf(w.x, v.x, a);
    a = fmaf(w.y, v.y, a);
    a = fmaf(w.z, v.z, a);
    a = fmaf(w.w, v.w, a);
    return a;
}

__device__ __forceinline__ float wave_max(float v) {
    #pragma unroll
    for (int off = 32; off > 0; off >>= 1) v = fmaxf(v, __shfl_xor(v, off, 64));
    return v;
}
__device__ __forceinline__ float wave_sum(float v) {
    #pragma unroll
    for (int off = 32; off > 0; off >>= 1) v += __shfl_xor(v, off, 64);
    return v;
}

// Block-cooperative GEMV: vout[r][d] = sum_f W[d][f]*vin[r][f] + bias[d]
// r = tid&3, dl = tid>>2; lanes 4t..4t+3 read identical weight addresses
// -> coalescer dedups -> W read once per block.
__device__ __forceinline__ void gemv_rows(
    const float* __restrict__ W, const float* __restrict__ bias,
    const float (*vin)[LD], float (*vout)[LD], int tid)
{
    const int r  = tid & 3;
    const int dl = tid >> 2;  // 0..63, wave-uniform dl<32 split
    const float4* v4 = (const float4*)vin[r];
    const float4* w0 = (const float4*)(W + (long)dl * DD);
    const float4* w1 = (const float4*)(W + (long)(dl + 64) * DD);
    float a0 = bias[dl];
    float a1 = bias[dl + 64];
    if (dl < 32) {
        const float4* w2 = (const float4*)(W + (long)(dl + 128) * DD);
        float a2 = bias[dl + 128];
        #pragma unroll 8
        for (int f = 0; f < 40; ++f) {
            const float4 v = v4[f];
            a0 = dot4acc(w0[f], v, a0);
            a1 = dot4acc(w1[f], v, a1);
            a2 = dot4acc(w2[f], v, a2);
        }
        vout[r][dl]       = a0;
        vout[r][dl + 64]  = a1;
        vout[r][dl + 128] = a2;
    } else {
        #pragma unroll 8
        for (int f = 0; f < 40; ++f) {
            const float4 v = v4[f];
            a0 = dot4acc(w0[f], v, a0);
            a1 = dot4acc(w1[f], v, a1);
        }
        vout[r][dl]      = a0;
        vout[r][dl + 64] = a1;
    }
}

// ---------------- setup: fold weight matrices (runs every launch) ----------
__global__ void setup_kernel(const float* __restrict__ ipw, const float* __restrict__ ipb,
                             const float* __restrict__ ow,  const float* __restrict__ ob,
                             float* __restrict__ ws)
{
    const int g = blockIdx.x * blockDim.x + threadIdx.x;
    const float inv = 0.07905694150420949f;  // 1/sqrt(160)
    if (g < 25600) {
        const int e = g / DD, f = g % DD;
        const float* wk = ipw + DD * DD;
        float a = 0.f;
        for (int d = 0; d < DD; ++d) a = fmaf(wk[d * DD + e], ipw[d * DD + f], a);
        ws[WS_M + g] = a * inv;
    } else if (g < 51200) {
        const int gg = g - 25600;
        const int i = gg / DD, f = gg % DD;
        const float* wv = ipw + 2 * DD * DD;
        float a = 0.f;
        for (int d = 0; d < DD; ++d) a = fmaf(ow[i * DD + d], wv[d * DD + f], a);
        ws[WS_V2 + gg] = a;
    } else if (g < 51360) {
        const int e = g - 51200;
        const float* wk = ipw + DD * DD;
        float a = 0.f;
        for (int d = 0; d < DD; ++d) a = fmaf(wk[d * DD + e], ipb[d], a);
        ws[WS_C + e] = a * inv;
    } else if (g < 51520) {
        const int f = g - 51360;
        float a = 0.f;
        for (int d = 0; d < DD; ++d) a = fmaf(ipw[d * DD + f], ipb[DD + d], a);
        ws[WS_U + f] = a * inv;
    } else if (g < 51680) {
        const int i = g - 51520;
        float a = ob[i];
        for (int d = 0; d < DD; ++d) a = fmaf(ow[i * DD + d], ipb[2 * DD + d], a);
        ws[WS_B2 + i] = a;
    } else if (g == 51680) {
        float a = 0.f;
        for (int d = 0; d < DD; ++d) a = fmaf(ipb[d], ipb[DD + d], a);
        ws[WS_S0] = a * inv;
    }
}

// ---------------- main ------------------------------------------------------
__global__ __launch_bounds__(256, 4)
void structure_learner_kernel(
    const float* __restrict__ x,
    const int*   __restrict__ target_node_ids,
    const int*   __restrict__ target_node_times,
    const int*   __restrict__ neighbor_ids,
    const int*   __restrict__ edge_time,
    const float* __restrict__ edge_weight,
    const float* __restrict__ gumbel_u,
    const float* __restrict__ te_w,
    const float* __restrict__ te_b,
    const float* __restrict__ mlp_w,
    const float* __restrict__ mlp_b,
    const float* __restrict__ ws,
    float* __restrict__ out_ao,
    float* __restrict__ out_new,
    float* __restrict__ out_mask)
{
    __shared__ __attribute__((aligned(16))) float s_qin[ROWS][LD];
    __shared__ __attribute__((aligned(16))) float s_qt[ROWS][LD];
    __shared__ __attribute__((aligned(16))) float s_wkv[ROWS][LD];
    __shared__ __attribute__((aligned(16))) float s_ao[ROWS][LD];
    __shared__ float s_attnw[ROWS][KK];
    __shared__ int   s_nid[ROWS][KK];
    __shared__ __attribute__((aligned(4))) _Float16 s_te[ROWS][KK][TE_STRIDE];

    const int tid  = threadIdx.x;
    const int wr   = tid >> 6;   // wave == row
    const int lane = tid & 63;
    const int b    = blockIdx.x * ROWS + wr;

    const float* Mw = ws + WS_M;
    const float* V2 = ws + WS_V2;
    const float* Cv = ws + WS_C;
    const float* Uv = ws + WS_U;
    const float* B2 = ws + WS_B2;
    const float  s0 = ws[WS_S0];

    // ---- P0: meta + q_in + te table (each cos exactly once; lane = k) ----
    {
        s_nid[wr][lane] = neighbor_ids[(long)b * KK + lane];
        const float etv = (float)edge_time[(long)b * KK + lane];
        const int tn = target_node_ids[b];
        const float2 tx = *(const float2*)(x + (long)tn * F_DIM + lane * 2);
        s_qin[wr][lane * 2]     = tx.x;
        s_qin[wr][lane * 2 + 1] = tx.y;
        if (lane < TE_DIM) {
            const float tt = (float)target_node_times[b];
            s_qin[wr][F_DIM + lane] = cosf(tt * te_w[lane] + te_b[lane]);
        }
        // te table row for k = lane: 16 packed dword writes
        #pragma unroll
        for (int jj = 0; jj < 16; ++jj) {
            union { _Float16 h[2]; unsigned u; } pk;
            pk.h[0] = (_Float16)cosf(etv * te_w[2 * jj]     + te_b[2 * jj]);
            pk.h[1] = (_Float16)cosf(etv * te_w[2 * jj + 1] + te_b[2 * jj + 1]);
            *(unsigned*)&s_te[wr][lane][2 * jj] = pk.u;
        }
    }
    __syncthreads();

    // ---- P1: q_tilde = M @ q_in + c (256 threads, 4 rows) ----
    gemv_rows(Mw, Cv, s_qin, s_qt, tid);
    __syncthreads();

    // ---- P2: scores + softmax (wave per row, lane = k) ----
    float aw;
    {
        // sbk = q_in . U + s0 (folded q . bk term)
        float p = s_qin[wr][lane] * Uv[lane];
        p = fmaf(s_qin[wr][lane + 64], Uv[lane + 64], p);
        if (lane < 32) p = fmaf(s_qin[wr][128 + lane], Uv[128 + lane], p);
        const float sbk = wave_sum(p) + s0;

        const int nidk = s_nid[wr][lane];
        const float4* xr  = (const float4*)(x + (long)nidk * F_DIM);
        const float4* qt4 = (const float4*)s_qt[wr];
        float acc = 0.f;
        #pragma unroll 8
        for (int f = 0; f < F_DIM / 4; ++f)
            acc = dot4acc(xr[f], qt4[f], acc);
        const float* qte = s_qt[wr] + F_DIM;
        #pragma unroll
        for (int jj = 0; jj < 16; ++jj) {
            union { _Float16 h[2]; unsigned u; } pk;
            pk.u = *(const unsigned*)&s_te[wr][lane][2 * jj];
            acc = fmaf(qte[2 * jj],     (float)pk.h[0], acc);
            acc = fmaf(qte[2 * jj + 1], (float)pk.h[1], acc);
        }
        const float sc = acc + sbk;
        const float m = wave_max(sc);
        const float e = expf(sc - m);
        const float l = wave_sum(e);
        aw = e / l;
        s_attnw[wr][lane] = aw;  // produced & consumed by this wave — no barrier
    }

    // ---- P3: wkv = sum_k attn_w[k] * kv[k] (wave per row, lane = feat pair) ----
    {
        float ax = 0.f, ay = 0.f, at = 0.f;
        const float* xb = x + lane * 2;
        const int lte = lane & 31;
        #pragma unroll 8
        for (int k = 0; k < KK; ++k) {
            const float wgt = s_attnw[wr][k];
            const int   nid = s_nid[wr][k];
            const float2 xv = *(const float2*)(xb + (long)nid * F_DIM);
            ax = fmaf(wgt, xv.x, ax);
            ay = fmaf(wgt, xv.y, ay);
            at = fmaf(wgt, (float)s_te[wr][k][lte], at);  // broadcast pairs, free
        }
        s_wkv[wr][lane * 2]     = ax;
        s_wkv[wr][lane * 2 + 1] = ay;
        if (lane < TE_DIM) s_wkv[wr][F_DIM + lane] = at;
    }
    __syncthreads();

    // ---- P4: ao = V2 @ wkv + b2 ----
    gemv_rows(V2, B2, s_wkv, s_ao, tid);
    __syncthreads();

    // ---- P5: epilogue (wave per row, lane = k) ----
    {
        float p = s_ao[wr][lane] * mlp_w[lane];
        p = fmaf(s_ao[wr][lane + 64], mlp_w[lane + 64], p);
        if (lane < 32) p = fmaf(s_ao[wr][lane + 128], mlp_w[lane + 128], p);
        const float base = wave_sum(p) + mlp_b[0];

        float* ao = out_ao + (long)b * DD;
        ao[lane]      = s_ao[wr][lane];
        ao[lane + 64] = s_ao[wr][lane + 64];
        if (lane < 32) ao[lane + 128] = s_ao[wr][lane + 128];

        const float u = gumbel_u[(long)b * KK + lane];
        const float g = -logf(-logf(u + 1e-10f) + 1e-10f);
        const float z = aw + g;  // TAU = 1.0
        const float m = wave_max(z);
        const float e = expf(z - m);
        const float l = wave_sum(e);
        out_mask[(long)b * KK + lane] = (e / l > 0.2f) ? 1.0f : 0.0f;

        const float ew  = edge_weight[(long)b * KK + lane];
        const float val = fmaf(ew, mlp_w[DD], base);
        out_new[(long)b * KK + lane] = (val >= 0.f) ? val : 0.01f * val;
    }
}

extern "C" void kernel_launch(void* const* d_in, const int* in_sizes, int n_in,
                              void* d_out, int out_size, void* d_ws, size_t ws_size,
                              hipStream_t stream) {
    const float* x   = (const float*)d_in[0];
    const int*   tni = (const int*)d_in[1];
    const int*   tnt = (const int*)d_in[2];
    const int*   nid = (const int*)d_in[3];
    const int*   et  = (const int*)d_in[4];
    const float* ew  = (const float*)d_in[5];
    const float* gu  = (const float*)d_in[6];
    const float* tew = (const float*)d_in[7];
    const float* teb = (const float*)d_in[8];
    const float* ipw = (const float*)d_in[9];
    const float* ipb = (const float*)d_in[10];
    const float* ow  = (const float*)d_in[11];
    const float* ob  = (const float*)d_in[12];
    const float* mw  = (const float*)d_in[13];
    const float* mb  = (const float*)d_in[14];

    float* wsf = (float*)d_ws;

    float* out      = (float*)d_out;
    float* out_ao   = out;
    float* out_new  = out + (long)NB * DD;
    float* out_mask = out + (long)NB * DD + (long)NB * KK;

    setup_kernel<<<(WS_TOT + 255) / 256, 256, 0, stream>>>(ipw, ipb, ow, ob, wsf);

    structure_learner_kernel<<<NB / ROWS, 256, 0, stream>>>(
        x, tni, tnt, nid, et, ew, gu, tew, teb, mw, mb, wsf,
        out_ao, out_new, out_mask);
}